// Round 2
// baseline (618.408 us; speedup 1.0000x reference)
//
#include <hip/hip_runtime.h>

#define B_GRAPHS 512
#define NPG 87
#define EPG 1392
#define NN (B_GRAPHS*NPG)        // 44544
#define NE (B_GRAPHS*EPG)        // 712704
#define HID 256
#define EMBD 768
#define APAD 88
#define ASZ (NPG*APAD)           // 7656
#define ADJSZ (B_GRAPHS*NPG*NPG) // 3875328

// ---------------- degree / dinv ----------------
__global__ __launch_bounds__(256) void k_deg_init(float* __restrict__ deg) {
    int i = blockIdx.x*256 + threadIdx.x;
    if (i < NN) deg[i] = 1.0f;   // self-loop weight
}

__global__ __launch_bounds__(256) void k_deg_acc(const int* __restrict__ dst,
                                                 const float* __restrict__ ew,
                                                 float* __restrict__ deg) {
    int e = blockIdx.x*256 + threadIdx.x;
    if (e < NE) atomicAdd(&deg[dst[e]], ew[e]);
}

__global__ __launch_bounds__(256) void k_dinv(const float* __restrict__ deg,
                                              float* __restrict__ dinv) {
    int i = blockIdx.x*256 + threadIdx.x;
    if (i < NN) dinv[i] = rsqrtf(deg[i]);   // deg >= 1 always
}

// ---------------- dense normalized adjacency, stored transposed At[s][d] = A[d][s] ----------------
__global__ __launch_bounds__(256) void k_buildA(const int* __restrict__ src,
                                                const int* __restrict__ dst,
                                                const float* __restrict__ ew,
                                                const float* __restrict__ dinv,
                                                float* __restrict__ At) {
    __shared__ float sA[ASZ];
    int g = blockIdx.x, tid = threadIdx.x;
    for (int i = tid; i < ASZ; i += 256) sA[i] = 0.f;
    __syncthreads();
    int base = g*NPG;
    for (int e = g*EPG + tid; e < (g+1)*EPG; e += 256) {
        int s = src[e], d = dst[e];
        float v = dinv[s]*ew[e]*dinv[d];
        atomicAdd(&sA[(s-base)*APAD + (d-base)], v);  // At[src][dst]
    }
    __syncthreads();
    if (tid < NPG) { float di = dinv[base+tid]; sA[tid*APAD+tid] += di*di; }
    __syncthreads();
    float* outp = At + (size_t)g*ASZ;
    for (int i = tid; i < ASZ; i += 256) outp[i] = sA[i];
}

// ---------------- T = h @ W  (no bias; bias added after aggregation) ----------------
template<int K>
__global__ __launch_bounds__(256) void k_gemm(const float* __restrict__ h, int rs,
                                              const float* __restrict__ W,
                                              float* __restrict__ T) {
    __shared__ float As[16*68];   // As[kk][r], transposed, padded stride 68
    __shared__ float Bs[16*64];   // Bs[kk][c]
    int tid = threadIdx.x;
    int bc = blockIdx.x*64;       // col block (4)
    int br = blockIdx.y*64;       // row block (696)
    int tx = tid & 15, ty = tid >> 4;
    int c0 = tx*4, r0 = ty*4;
    float acc[4][4] = {};
    for (int k0 = 0; k0 < K; k0 += 16) {
        #pragma unroll
        for (int i = 0; i < 4; ++i) {
            int flat = tid + i*256;
            int kk = flat & 15, r = flat >> 4;
            As[kk*68 + r] = (k0+kk < K) ? h[(size_t)(br+r)*rs + k0+kk] : 0.f;
        }
        #pragma unroll
        for (int i = 0; i < 4; ++i) {
            int flat = tid + i*256;
            int c = flat & 63, kk = flat >> 6;
            Bs[kk*64 + c] = (k0+kk < K) ? W[(size_t)(k0+kk)*HID + bc + c] : 0.f;
        }
        __syncthreads();
        #pragma unroll
        for (int kk = 0; kk < 16; ++kk) {
            float4 a4 = *(const float4*)&As[kk*68 + r0];
            float4 b4 = *(const float4*)&Bs[kk*64 + c0];
            float av[4] = {a4.x,a4.y,a4.z,a4.w};
            float bv[4] = {b4.x,b4.y,b4.z,b4.w};
            #pragma unroll
            for (int ii = 0; ii < 4; ++ii)
                #pragma unroll
                for (int jj = 0; jj < 4; ++jj)
                    acc[ii][jj] += av[ii]*bv[jj];
        }
        __syncthreads();
    }
    #pragma unroll
    for (int ii = 0; ii < 4; ++ii) {
        float4 o = make_float4(acc[ii][0],acc[ii][1],acc[ii][2],acc[ii][3]);
        *(float4*)&T[(size_t)(br+r0+ii)*HID + bc + c0] = o;
    }
}

// ---------------- h_out = relu(A @ T + b), write into emb[:, off:off+256] ----------------
__global__ __launch_bounds__(512) void k_agg(const float* __restrict__ T,
                                             const float* __restrict__ At,
                                             const float* __restrict__ bias,
                                             float* __restrict__ emb, int off) {
    __shared__ float sAt[ASZ];        // At[j][r] (= A[r][j]), stride 88
    __shared__ float sT[NPG*HID];     // T rows of this graph
    int g = blockIdx.x, tid = threadIdx.x;
    const float* gA = At + (size_t)g*ASZ;
    for (int i = tid; i < ASZ; i += 512) sAt[i] = gA[i];
    const float* gT = T + (size_t)g*NPG*HID;
    for (int i = tid; i < NPG*HID; i += 512) sT[i] = gT[i];
    __syncthreads();
    for (int t = tid; t < 22*64; t += 512) {   // 4x4 tiles over [88 x 256]
        int r0 = (t >> 6) * 4, c0 = (t & 63) * 4;
        float acc[4][4] = {};
        for (int j = 0; j < NPG; ++j) {
            float4 a4 = *(const float4*)&sAt[j*APAD + r0];   // broadcast within wave
            float4 t4 = *(const float4*)&sT[j*HID + c0];
            float av[4] = {a4.x,a4.y,a4.z,a4.w};
            float tv[4] = {t4.x,t4.y,t4.z,t4.w};
            #pragma unroll
            for (int ii = 0; ii < 4; ++ii)
                #pragma unroll
                for (int jj = 0; jj < 4; ++jj)
                    acc[ii][jj] += av[ii]*tv[jj];
        }
        float4 b4 = *(const float4*)&bias[c0];
        float bv[4] = {b4.x,b4.y,b4.z,b4.w};
        #pragma unroll
        for (int ii = 0; ii < 4; ++ii) {
            int r = r0 + ii;
            if (r < NPG) {
                float4 o;
                o.x = fmaxf(acc[ii][0]+bv[0], 0.f);
                o.y = fmaxf(acc[ii][1]+bv[1], 0.f);
                o.z = fmaxf(acc[ii][2]+bv[2], 0.f);
                o.w = fmaxf(acc[ii][3]+bv[3], 0.f);
                *(float4*)&emb[((size_t)g*NPG + r)*EMBD + off + c0] = o;
            }
        }
    }
}

// ---------------- mean pool + logits ----------------
__global__ __launch_bounds__(256) void k_pool(const float* __restrict__ emb,
                                              const float* __restrict__ Wc,
                                              const float* __restrict__ bc,
                                              float* __restrict__ outp) {
    int g = blockIdx.x, tid = threadIdx.x;
    float p0 = 0.f, p1 = 0.f;
    #pragma unroll
    for (int cc = 0; cc < 3; ++cc) {
        int c = tid + cc*256;
        float s = 0.f;
        for (int r = 0; r < NPG; ++r) s += emb[((size_t)g*NPG + r)*EMBD + c];
        float ge = s * (1.0f/87.0f);
        p0 += ge * Wc[c*2+0];
        p1 += ge * Wc[c*2+1];
    }
    __shared__ float red0[256];
    __shared__ float red1[256];
    red0[tid] = p0; red1[tid] = p1;
    __syncthreads();
    for (int s = 128; s > 0; s >>= 1) {
        if (tid < s) { red0[tid] += red0[tid+s]; red1[tid] += red1[tid+s]; }
        __syncthreads();
    }
    if (tid == 0) {
        outp[ADJSZ + g*2 + 0] = red0[0] + bc[0];
        outp[ADJSZ + g*2 + 1] = red1[0] + bc[1];
    }
}

// ---------------- decoder: relu(ne @ ne^T) per graph ----------------
__global__ __launch_bounds__(512) void k_adj(const float* __restrict__ emb,
                                             float* __restrict__ outp) {
    __shared__ float sH[APAD*HID];   // 88 x 256
    int g = blockIdx.x, tid = threadIdx.x;
    float acc[4][4] = {};
    int ti = tid/22, tj = tid%22;    // 22x22 = 484 tiles of 4x4 over [88x88]
    int i0 = ti*4, j0 = tj*4;
    int rot = (tid & 7) * 4;         // bank-spread rotation on d
    for (int layer = 0; layer < 3; ++layer) {
        __syncthreads();
        for (int idx = tid; idx < APAD*HID; idx += 512) {
            int r = idx >> 8, c = idx & 255;
            sH[idx] = (r < NPG) ? emb[((size_t)g*NPG + r)*EMBD + layer*HID + c] : 0.f;
        }
        __syncthreads();
        if (tid < 484) {
            for (int d0 = 0; d0 < HID; d0 += 4) {
                int dd = (d0 + rot) & 255;
                float4 a[4], b[4];
                #pragma unroll
                for (int ii = 0; ii < 4; ++ii) a[ii] = *(const float4*)&sH[(i0+ii)*HID + dd];
                #pragma unroll
                for (int jj = 0; jj < 4; ++jj) b[jj] = *(const float4*)&sH[(j0+jj)*HID + dd];
                #pragma unroll
                for (int ii = 0; ii < 4; ++ii)
                    #pragma unroll
                    for (int jj = 0; jj < 4; ++jj)
                        acc[ii][jj] += a[ii].x*b[jj].x + a[ii].y*b[jj].y
                                     + a[ii].z*b[jj].z + a[ii].w*b[jj].w;
            }
        }
    }
    if (tid < 484) {
        #pragma unroll
        for (int ii = 0; ii < 4; ++ii) {
            int i = i0 + ii;
            if (i < NPG) {
                #pragma unroll
                for (int jj = 0; jj < 4; ++jj) {
                    int j = j0 + jj;
                    if (j < NPG)
                        outp[(size_t)g*NPG*NPG + i*NPG + j] = fmaxf(acc[ii][jj], 0.f);
                }
            }
        }
    }
}

extern "C" void kernel_launch(void* const* d_in, const int* in_sizes, int n_in,
                              void* d_out, int out_size, void* d_ws, size_t ws_size,
                              hipStream_t stream) {
    const float* x   = (const float*)d_in[0];
    const int*   ei  = (const int*)d_in[1];
    const float* ew  = (const float*)d_in[2];
    // d_in[3] = batch (unused: graphs are uniform 87 nodes)
    const float* W1  = (const float*)d_in[4];
    const float* b1  = (const float*)d_in[5];
    const float* W2  = (const float*)d_in[6];
    const float* b2  = (const float*)d_in[7];
    const float* W3  = (const float*)d_in[8];
    const float* b3  = (const float*)d_in[9];
    const float* Wc  = (const float*)d_in[10];
    const float* bc  = (const float*)d_in[11];
    float* outp = (float*)d_out;

    float* ws   = (float*)d_ws;
    float* deg  = ws;                          // NN
    float* dinv = deg + NN;                    // NN
    float* At   = dinv + NN;                   // B*ASZ
    float* T    = At + (size_t)B_GRAPHS*ASZ;   // NN*HID
    float* emb  = T + (size_t)NN*HID;          // NN*EMBD

    const int* srcp = ei;
    const int* dstp = ei + NE;

    k_deg_init<<<(NN+255)/256, 256, 0, stream>>>(deg);
    k_deg_acc <<<(NE+255)/256, 256, 0, stream>>>(dstp, ew, deg);
    k_dinv    <<<(NN+255)/256, 256, 0, stream>>>(deg, dinv);
    k_buildA  <<<B_GRAPHS, 256, 0, stream>>>(srcp, dstp, ew, dinv, At);

    // layer 1: T = x @ W1 ; emb[:,0:256] = relu(A@T + b1)
    k_gemm<87><<<dim3(4,696), 256, 0, stream>>>(x, NPG, W1, T);
    k_agg<<<B_GRAPHS, 512, 0, stream>>>(T, At, b1, emb, 0);
    // layer 2
    k_gemm<256><<<dim3(4,696), 256, 0, stream>>>(emb + 0, EMBD, W2, T);
    k_agg<<<B_GRAPHS, 512, 0, stream>>>(T, At, b2, emb, 256);
    // layer 3
    k_gemm<256><<<dim3(4,696), 256, 0, stream>>>(emb + 256, EMBD, W3, T);
    k_agg<<<B_GRAPHS, 512, 0, stream>>>(T, At, b3, emb, 512);

    k_pool<<<B_GRAPHS, 256, 0, stream>>>(emb, Wc, bc, outp);
    k_adj <<<B_GRAPHS, 512, 0, stream>>>(emb, outp);
}

// Round 3
// 249.621 us; speedup vs baseline: 2.4774x; 2.4774x over previous
//
#include <hip/hip_runtime.h>

#define B_GRAPHS 512
#define NPG 87
#define NPGP 96
#define EPG 1392
#define NN (B_GRAPHS*NPG)        // 44544
#define NE (B_GRAPHS*EPG)        // 712704
#define HID 256
#define EMBD 768
#define ADJSZ (B_GRAPHS*NPG*NPG) // 3875328

typedef __attribute__((ext_vector_type(8))) short bf16x8;
typedef __attribute__((ext_vector_type(4))) float f32x4;

__device__ __forceinline__ ushort f2b(float f) {
    uint u = __float_as_uint(f);
    return (ushort)((u + 0x7FFFu + ((u >> 16) & 1u)) >> 16);
}
__device__ __forceinline__ float b2f(ushort h) {
    uint u = ((uint)h) << 16;
    return __uint_as_float(u);
}

// ---------------- casts ----------------
__global__ __launch_bounds__(256) void k_cast_x(const float* __restrict__ x,
                                                ushort* __restrict__ xb) {
    int idx = blockIdx.x*256 + threadIdx.x;      // over NN*96
    int r = idx / NPGP, c = idx - r*NPGP;
    xb[idx] = (c < NPG) ? f2b(x[(size_t)r*NPG + c]) : (ushort)0;
}

// W [K][256] f32 -> WT [256][Kpad] bf16 (transposed, zero-padded)
__global__ __launch_bounds__(256) void k_cast_wt(const float* __restrict__ W1,
                                                 const float* __restrict__ W2,
                                                 const float* __restrict__ W3,
                                                 ushort* __restrict__ WT1,
                                                 ushort* __restrict__ WT2,
                                                 ushort* __restrict__ WT3) {
    int y = blockIdx.y;
    const float* W = (y == 0) ? W1 : (y == 1) ? W2 : W3;
    ushort* WT = (y == 0) ? WT1 : (y == 1) ? WT2 : WT3;
    int K = (y == 0) ? NPG : HID;
    int Kp = (y == 0) ? NPGP : HID;
    int idx = blockIdx.x*256 + threadIdx.x;
    if (idx >= 256*Kp) return;
    int c = idx / Kp, k = idx - c*Kp;
    WT[idx] = (k < K) ? f2b(W[(size_t)k*HID + c]) : (ushort)0;
}

// ---------------- degree / dinv ----------------
__global__ __launch_bounds__(256) void k_deg_init(float* __restrict__ deg) {
    int i = blockIdx.x*256 + threadIdx.x;
    if (i < NN) deg[i] = 1.0f;
}
__global__ __launch_bounds__(256) void k_deg_acc(const int* __restrict__ dst,
                                                 const float* __restrict__ ew,
                                                 float* __restrict__ deg) {
    int e = blockIdx.x*256 + threadIdx.x;
    if (e < NE) atomicAdd(&deg[dst[e]], ew[e]);
}
__global__ __launch_bounds__(256) void k_dinv(const float* __restrict__ deg,
                                              float* __restrict__ dinv) {
    int i = blockIdx.x*256 + threadIdx.x;
    if (i < NN) dinv[i] = rsqrtf(deg[i]);
}

// ---------------- dense normalized adjacency Ab[g][d][s], bf16, 96x96 zero-padded ----------------
__global__ __launch_bounds__(256) void k_buildA(const int* __restrict__ src,
                                                const int* __restrict__ dst,
                                                const float* __restrict__ ew,
                                                const float* __restrict__ dinv,
                                                ushort* __restrict__ Ab) {
    __shared__ float sA[NPGP*NPGP];
    int g = blockIdx.x, tid = threadIdx.x;
    for (int i = tid; i < NPGP*NPGP; i += 256) sA[i] = 0.f;
    __syncthreads();
    int base = g*NPG;
    for (int e = g*EPG + tid; e < (g+1)*EPG; e += 256) {
        int s = src[e], d = dst[e];
        float v = dinv[s]*ew[e]*dinv[d];
        atomicAdd(&sA[(d-base)*NPGP + (s-base)], v);   // A[dst][src]
    }
    __syncthreads();
    if (tid < NPG) { float di = dinv[base+tid]; sA[tid*NPGP+tid] += di*di; }
    __syncthreads();
    ushort* outp = Ab + (size_t)g*NPGP*NPGP;
    for (int i = tid; i < NPGP*NPGP; i += 256) outp[i] = f2b(sA[i]);
}

// ---------------- T[node][feat] = Hin @ W  via MFMA (m=feat, n=node) ----------------
// MA = WT[c][k] (k-contig), MBt = Hin[node][k] (k-contig). D: col=node, rows=feat.
#define GSTR 56   // LDS row stride (bf16 elems): 112B, 16B-aligned, 2-way banks (free)
template<int KTOT, int RSTRIDE>
__global__ __launch_bounds__(256) void k_gemm(const ushort* __restrict__ Hin,
                                              const ushort* __restrict__ WT, int wts,
                                              ushort* __restrict__ T) {
    __shared__ ushort sW[128*GSTR];
    __shared__ ushort sH[128*GSTR];
    const int tid = threadIdx.x;
    const int wave = tid >> 6, lane = tid & 63;
    const int cb = blockIdx.x*128;        // feat block (2)
    const int nb = blockIdx.y*128;        // node block (348)
    const int mh = (wave >> 1)*64, nh = (wave & 1)*64;
    const int l15 = lane & 15, lk = (lane >> 4)*8;
    f32x4 acc[4][4] = {};
    for (int k0 = 0; k0 < KTOT; k0 += 32) {
        __syncthreads();
        #pragma unroll
        for (int it = 0; it < 2; ++it) {
            int flat = tid + it*256;
            int r = flat >> 2, kq = (flat & 3)*8;
            *(bf16x8*)&sW[r*GSTR + kq] = *(const bf16x8*)&WT[(size_t)(cb + r)*wts + k0 + kq];
            *(bf16x8*)&sH[r*GSTR + kq] = *(const bf16x8*)&Hin[(size_t)(nb + r)*RSTRIDE + k0 + kq];
        }
        __syncthreads();
        bf16x8 af[4], bfr[4];
        #pragma unroll
        for (int t = 0; t < 4; ++t) {
            af[t]  = *(const bf16x8*)&sW[(mh + t*16 + l15)*GSTR + lk];
            bfr[t] = *(const bf16x8*)&sH[(nh + t*16 + l15)*GSTR + lk];
        }
        #pragma unroll
        for (int i = 0; i < 4; ++i)
            #pragma unroll
            for (int j = 0; j < 4; ++j)
                acc[i][j] = __builtin_amdgcn_mfma_f32_16x16x32_bf16(af[i], bfr[j], acc[i][j], 0, 0, 0);
    }
    const int rq = (lane >> 4)*4;
    #pragma unroll
    for (int i = 0; i < 4; ++i) {
        int c0 = cb + mh + i*16 + rq;
        #pragma unroll
        for (int j = 0; j < 4; ++j) {
            int n = nb + nh + j*16 + l15;
            ushort4 o;
            o.x = f2b(acc[i][j][0]); o.y = f2b(acc[i][j][1]);
            o.z = f2b(acc[i][j][2]); o.w = f2b(acc[i][j][3]);
            *(ushort4*)&T[(size_t)n*HID + c0] = o;
        }
    }
}

// ---------------- emb[d][off+c] = relu(A@T + b) via MFMA (m=feat, n=node) ----------------
// MA = Tt[c][s] (LDS transpose of T_g), MBt = Ab[d][s]. D: col=node d, rows=feat c.
#define ASTR 104  // 208B stride: 16B-aligned, 2-way banks
__global__ __launch_bounds__(256) void k_agg(const ushort* __restrict__ T,
                                             const ushort* __restrict__ Ab,
                                             const float* __restrict__ bias,
                                             ushort* __restrict__ emb, int off) {
    __shared__ ushort sTt[128*ASTR];
    __shared__ ushort sA[NPGP*ASTR];
    const int tid = threadIdx.x;
    const int wave = tid >> 6, lane = tid & 63;
    const int g = blockIdx.y, f0 = blockIdx.x*128;
    // load A (vector, rows padded to ASTR)
    #pragma unroll
    for (int it = 0; it < 5; ++it) {
        int flat = tid + it*256;
        if (flat < NPGP*NPGP/8) {
            int r = flat / 12, kq = (flat - r*12)*8;
            *(bf16x8*)&sA[r*ASTR + kq] = *(const bf16x8*)&Ab[(size_t)g*NPGP*NPGP + r*NPGP + kq];
        }
    }
    // load + transpose T_g: sTt[c][s] = T[g*87+s][f0+c]; s-contiguous lanes -> conflict-free LDS writes
    for (int it = 0; it < 44; ++it) {
        int idx = tid + it*256;
        if (idx < NPG*128) {
            int c = idx / NPG, s = idx - c*NPG;
            sTt[c*ASTR + s] = T[((size_t)g*NPG + s)*HID + f0 + c];
        }
    }
    // zero-pad s = 87..95
    #pragma unroll
    for (int it = 0; it < 5; ++it) {
        int idx = tid + it*256;
        if (idx < 128*9) {
            int c = idx / 9, s = NPG + (idx - c*9);
            sTt[c*ASTR + s] = 0;
        }
    }
    __syncthreads();
    const int l15 = lane & 15, lk = (lane >> 4)*8;
    f32x4 acc[2][6] = {};
    #pragma unroll
    for (int ks = 0; ks < 3; ++ks) {
        bf16x8 af[2], bfr[6];
        #pragma unroll
        for (int i = 0; i < 2; ++i)
            af[i] = *(const bf16x8*)&sTt[((wave*2 + i)*16 + l15)*ASTR + ks*32 + lk];
        #pragma unroll
        for (int j = 0; j < 6; ++j)
            bfr[j] = *(const bf16x8*)&sA[(j*16 + l15)*ASTR + ks*32 + lk];
        #pragma unroll
        for (int i = 0; i < 2; ++i)
            #pragma unroll
            for (int j = 0; j < 6; ++j)
                acc[i][j] = __builtin_amdgcn_mfma_f32_16x16x32_bf16(af[i], bfr[j], acc[i][j], 0, 0, 0);
    }
    const int rq = (lane >> 4)*4;
    #pragma unroll
    for (int i = 0; i < 2; ++i) {
        int c0 = f0 + (wave*2 + i)*16 + rq;
        float4 bv = *(const float4*)&bias[c0];
        #pragma unroll
        for (int j = 0; j < 6; ++j) {
            int d = j*16 + l15;
            if (d < NPG) {
                ushort4 o;
                o.x = f2b(fmaxf(acc[i][j][0] + bv.x, 0.f));
                o.y = f2b(fmaxf(acc[i][j][1] + bv.y, 0.f));
                o.z = f2b(fmaxf(acc[i][j][2] + bv.z, 0.f));
                o.w = f2b(fmaxf(acc[i][j][3] + bv.w, 0.f));
                *(ushort4*)&emb[((size_t)g*NPG + d)*EMBD + off + c0] = o;
            }
        }
    }
}

// ---------------- decoder: relu(ne @ ne^T) per graph via MFMA ----------------
#define ESTR 264  // 528B stride: 16B-aligned, 2-way banks
__global__ __launch_bounds__(256) void k_dec(const ushort* __restrict__ emb,
                                             float* __restrict__ outp) {
    __shared__ ushort sE[NPGP*ESTR];
    const int tid = threadIdx.x;
    const int wave = tid >> 6, lane = tid & 63;
    const int g = blockIdx.x;
    const int it0 = (wave >> 1)*3, jt0 = (wave & 1)*3;
    const int l15 = lane & 15, lk = (lane >> 4)*8;
    f32x4 acc[3][3] = {};
    for (int ch = 0; ch < 3; ++ch) {
        __syncthreads();
        #pragma unroll
        for (int it = 0; it < 12; ++it) {
            int flat = tid + it*256;           // over 96*32
            int r = flat >> 5, p = flat & 31;
            bf16x8 v = {};
            if (r < NPG)
                v = *(const bf16x8*)&emb[((size_t)g*NPG + r)*EMBD + ch*HID + p*8];
            *(bf16x8*)&sE[r*ESTR + p*8] = v;
        }
        __syncthreads();
        #pragma unroll
        for (int ks = 0; ks < 8; ++ks) {
            bf16x8 af[3], bfr[3];
            #pragma unroll
            for (int t = 0; t < 3; ++t) {
                af[t]  = *(const bf16x8*)&sE[((it0 + t)*16 + l15)*ESTR + ks*32 + lk];
                bfr[t] = *(const bf16x8*)&sE[((jt0 + t)*16 + l15)*ESTR + ks*32 + lk];
            }
            #pragma unroll
            for (int i = 0; i < 3; ++i)
                #pragma unroll
                for (int j = 0; j < 3; ++j)
                    acc[i][j] = __builtin_amdgcn_mfma_f32_16x16x32_bf16(af[i], bfr[j], acc[i][j], 0, 0, 0);
        }
    }
    const int rq = (lane >> 4)*4;
    #pragma unroll
    for (int i = 0; i < 3; ++i) {
        #pragma unroll
        for (int j = 0; j < 3; ++j) {
            int jj = (jt0 + j)*16 + l15;
            if (jj < NPG) {
                #pragma unroll
                for (int r = 0; r < 4; ++r) {
                    int ii = (it0 + i)*16 + rq + r;
                    if (ii < NPG)
                        outp[((size_t)g*NPG + ii)*NPG + jj] = fmaxf(acc[i][j][r], 0.f);
                }
            }
        }
    }
}

// ---------------- mean pool + logits ----------------
__global__ __launch_bounds__(256) void k_pool(const ushort* __restrict__ emb,
                                              const float* __restrict__ Wc,
                                              const float* __restrict__ bc,
                                              float* __restrict__ outp) {
    int g = blockIdx.x, tid = threadIdx.x;
    float p0 = 0.f, p1 = 0.f;
    #pragma unroll
    for (int cc = 0; cc < 3; ++cc) {
        int c = tid + cc*256;
        float s = 0.f;
        for (int r = 0; r < NPG; ++r) s += b2f(emb[((size_t)g*NPG + r)*EMBD + c]);
        float ge = s * (1.0f/87.0f);
        p0 += ge * Wc[c*2+0];
        p1 += ge * Wc[c*2+1];
    }
    __shared__ float red0[256];
    __shared__ float red1[256];
    red0[tid] = p0; red1[tid] = p1;
    __syncthreads();
    for (int s = 128; s > 0; s >>= 1) {
        if (tid < s) { red0[tid] += red0[tid+s]; red1[tid] += red1[tid+s]; }
        __syncthreads();
    }
    if (tid == 0) {
        outp[ADJSZ + g*2 + 0] = red0[0] + bc[0];
        outp[ADJSZ + g*2 + 1] = red1[0] + bc[1];
    }
}

extern "C" void kernel_launch(void* const* d_in, const int* in_sizes, int n_in,
                              void* d_out, int out_size, void* d_ws, size_t ws_size,
                              hipStream_t stream) {
    const float* x   = (const float*)d_in[0];
    const int*   ei  = (const int*)d_in[1];
    const float* ew  = (const float*)d_in[2];
    const float* W1  = (const float*)d_in[4];
    const float* b1  = (const float*)d_in[5];
    const float* W2  = (const float*)d_in[6];
    const float* b2  = (const float*)d_in[7];
    const float* W3  = (const float*)d_in[8];
    const float* b3  = (const float*)d_in[9];
    const float* Wc  = (const float*)d_in[10];
    const float* bc  = (const float*)d_in[11];
    float* outp = (float*)d_out;

    char* ws = (char*)d_ws;
    float*  deg  = (float*)ws;                      ws += (size_t)NN*4;
    float*  dinv = (float*)ws;                      ws += (size_t)NN*4;
    ushort* Ab   = (ushort*)ws;                     ws += (size_t)B_GRAPHS*NPGP*NPGP*2;
    ushort* xb   = (ushort*)ws;                     ws += (size_t)NN*NPGP*2;
    ushort* WT1  = (ushort*)ws;                     ws += (size_t)HID*NPGP*2;
    ushort* WT2  = (ushort*)ws;                     ws += (size_t)HID*HID*2;
    ushort* WT3  = (ushort*)ws;                     ws += (size_t)HID*HID*2;
    ushort* T    = (ushort*)ws;                     ws += (size_t)NN*HID*2;
    ushort* emb  = (ushort*)ws;                     ws += (size_t)NN*EMBD*2;

    const int* srcp = ei;
    const int* dstp = ei + NE;

    k_cast_x <<<NN*NPGP/256, 256, 0, stream>>>(x, xb);
    k_cast_wt<<<dim3(256,3), 256, 0, stream>>>(W1, W2, W3, WT1, WT2, WT3);
    k_deg_init<<<NN/256, 256, 0, stream>>>(deg);
    k_deg_acc <<<NE/256, 256, 0, stream>>>(dstp, ew, deg);
    k_dinv    <<<NN/256, 256, 0, stream>>>(deg, dinv);
    k_buildA  <<<B_GRAPHS, 256, 0, stream>>>(srcp, dstp, ew, dinv, Ab);

    // layer 1
    k_gemm<NPGP,NPGP><<<dim3(2,348), 256, 0, stream>>>(xb, WT1, NPGP, T);
    k_agg<<<dim3(2,B_GRAPHS), 256, 0, stream>>>(T, Ab, b1, emb, 0);
    // layer 2
    k_gemm<HID,EMBD><<<dim3(2,348), 256, 0, stream>>>(emb, WT2, HID, T);
    k_agg<<<dim3(2,B_GRAPHS), 256, 0, stream>>>(T, Ab, b2, emb, 256);
    // layer 3
    k_gemm<HID,EMBD><<<dim3(2,348), 256, 0, stream>>>(emb + 256, WT3, HID, T);
    k_agg<<<dim3(2,B_GRAPHS), 256, 0, stream>>>(T, Ab, b3, emb, 512);

    k_pool<<<B_GRAPHS, 256, 0, stream>>>(emb, Wc, bc, outp);
    k_dec <<<B_GRAPHS, 256, 0, stream>>>(emb, outp);
}

// Round 4
// 122.763 us; speedup vs baseline: 5.0374x; 2.0334x over previous
//
#include <hip/hip_runtime.h>

#define B_GRAPHS 512
#define NPG 87
#define NPGP 96
#define EPG 1392
#define NN (B_GRAPHS*NPG)        // 44544
#define NE (B_GRAPHS*EPG)        // 712704
#define HID 256
#define EMBD 768
#define ADJSZ (B_GRAPHS*NPG*NPG) // 3875328
#define TSTR 104                 // sTt row stride (elems): 208B, 2-way banks (free)

typedef __attribute__((ext_vector_type(8))) short bf16x8;
typedef __attribute__((ext_vector_type(4))) float f32x4;

__device__ __forceinline__ ushort f2b(float f) {
    uint u = __float_as_uint(f);
    return (ushort)((u + 0x7FFFu + ((u >> 16) & 1u)) >> 16);
}

// ---- W [K][256] f32 -> WT [256][Kp] bf16 (transposed, zero-padded) ----
__global__ __launch_bounds__(256) void k_cast_wt(const float* __restrict__ W1,
                                                 const float* __restrict__ W2,
                                                 const float* __restrict__ W3,
                                                 ushort* __restrict__ WT1,
                                                 ushort* __restrict__ WT2,
                                                 ushort* __restrict__ WT3) {
    int y = blockIdx.y;
    const float* W = (y == 0) ? W1 : (y == 1) ? W2 : W3;
    ushort* WT = (y == 0) ? WT1 : (y == 1) ? WT2 : WT3;
    int K  = (y == 0) ? NPG : HID;
    int Kp = (y == 0) ? NPGP : HID;
    int idx = blockIdx.x*256 + threadIdx.x;
    if (idx >= 256*Kp) return;
    int c = idx / Kp, k = idx - c*Kp;
    WT[idx] = (k < K) ? f2b(W[(size_t)k*HID + c]) : (ushort)0;
}

// ---- dense normalized adjacency Ab[g][d][s], bf16, 96x96, deg/dinv computed locally ----
__global__ __launch_bounds__(256) void k_buildA(const int* __restrict__ src,
                                                const int* __restrict__ dst,
                                                const float* __restrict__ ew,
                                                ushort* __restrict__ Ab) {
    __shared__ float sA[NPGP*NPGP];
    __shared__ float sdeg[NPGP];
    __shared__ float sdi[NPGP];
    int g = blockIdx.x, tid = threadIdx.x;
    for (int i = tid; i < NPGP*NPGP; i += 256) sA[i] = 0.f;
    if (tid < NPGP) sdeg[tid] = 1.0f;   // self-loop
    int base = g*NPG;
    int sl[6], dl[6]; float wv[6];
    #pragma unroll
    for (int it = 0; it < 6; ++it) {
        int eo = tid + it*256;
        bool v = (eo < EPG);
        int e = g*EPG + (v ? eo : 0);
        sl[it] = src[e] - base;
        dl[it] = dst[e] - base;
        wv[it] = v ? ew[e] : 0.f;
    }
    __syncthreads();
    #pragma unroll
    for (int it = 0; it < 6; ++it) atomicAdd(&sdeg[dl[it]], wv[it]);
    __syncthreads();
    if (tid < NPGP) sdi[tid] = rsqrtf(sdeg[tid]);
    __syncthreads();
    #pragma unroll
    for (int it = 0; it < 6; ++it)
        atomicAdd(&sA[dl[it]*NPGP + sl[it]], sdi[sl[it]]*wv[it]*sdi[dl[it]]);
    __syncthreads();
    if (tid < NPG) { float di = sdi[tid]; sA[tid*NPGP + tid] += di*di; }
    __syncthreads();
    ushort* outp = Ab + (size_t)g*NPGP*NPGP;
    for (int i = tid; i < NPGP*NPGP; i += 256) outp[i] = f2b(sA[i]);
}

// ---- fused layer: emb_out = relu(A @ (Hin @ W) + b); gsum partials fused ----
// Block = one graph. Stage1: a=H rows(node,k), b=WT rows(feat,k) -> sTt[feat][node].
// Stage2: a=sTt rows(feat,s), b=Ab rows(d,s) -> emb[d][feat], column sums -> gsum.
template<int K>
__global__ __launch_bounds__(256, 2) void k_layer(const float* __restrict__ xf,
                                                  const ushort* __restrict__ hin,
                                                  const ushort* __restrict__ WT,
                                                  const float* __restrict__ bias,
                                                  const ushort* __restrict__ Ab,
                                                  ushort* __restrict__ eout,
                                                  float* __restrict__ gout) {
    constexpr int HSTR  = (K == 96) ? TSTR : 136;   // 2-way bank stride
    constexpr int CHUNK = (K == 96) ? 96 : 128;
    constexpr int NCH   = K / CHUNK;
    constexpr int KS    = CHUNK / 32;
    __shared__ ushort sH[NPGP*HSTR];
    __shared__ ushort sTt[HID*TSTR];
    const int tid = threadIdx.x, wave = tid >> 6, lane = tid & 63;
    const int g = blockIdx.x;
    const int l15 = lane & 15, q = lane >> 4, lk = q*8;

    // ---------- stage 1: T = Hin @ W ----------
    f32x4 acc[6][4] = {};
    for (int kh = 0; kh < NCH; ++kh) {
        __syncthreads();
        if constexpr (K == 96) {
            for (int idx = tid; idx < NPGP*NPGP; idx += 256) {
                int r = idx / NPGP, c = idx - r*NPGP;
                sH[r*HSTR + c] = (r < NPG && c < NPG)
                               ? f2b(xf[((size_t)g*NPG + r)*NPG + c]) : (ushort)0;
            }
        } else {
            #pragma unroll
            for (int it = 0; it < 6; ++it) {
                int flat = tid + it*256;          // 96*16
                int r = flat >> 4, cv = flat & 15;
                bf16x8 v = {};
                if (r < NPG)
                    v = *(const bf16x8*)&hin[((size_t)g*NPG + r)*EMBD + kh*CHUNK + cv*8];
                *(bf16x8*)&sH[r*HSTR + cv*8] = v;
            }
        }
        __syncthreads();
        #pragma unroll
        for (int ks = 0; ks < KS; ++ks) {
            bf16x8 af[6], bfr[4];
            #pragma unroll
            for (int i = 0; i < 6; ++i)
                af[i] = *(const bf16x8*)&sH[(i*16 + l15)*HSTR + ks*32 + lk];
            #pragma unroll
            for (int j = 0; j < 4; ++j)
                bfr[j] = *(const bf16x8*)&WT[(size_t)(wave*64 + j*16 + l15)*K + kh*CHUNK + ks*32 + lk];
            #pragma unroll
            for (int i = 0; i < 6; ++i)
                #pragma unroll
                for (int j = 0; j < 4; ++j)
                    acc[i][j] = __builtin_amdgcn_mfma_f32_16x16x32_bf16(af[i], bfr[j], acc[i][j], 0, 0, 0);
        }
    }
    // store T^t -> LDS (reg space = node, l15 = feat)
    #pragma unroll
    for (int i = 0; i < 6; ++i) {
        #pragma unroll
        for (int j = 0; j < 4; ++j) {
            int feat = wave*64 + j*16 + l15;
            int n0 = i*16 + q*4;
            ushort4 o;
            o.x = f2b(acc[i][j][0]); o.y = f2b(acc[i][j][1]);
            o.z = f2b(acc[i][j][2]); o.w = f2b(acc[i][j][3]);
            *(ushort4*)&sTt[feat*TSTR + n0] = o;
        }
    }
    __syncthreads();

    // ---------- stage 2: E = A @ T ----------
    f32x4 acc2[4][6] = {};
    const ushort* AbG = Ab + (size_t)g*NPGP*NPGP;
    #pragma unroll
    for (int ks = 0; ks < 3; ++ks) {
        bf16x8 af2[4], bf2[6];
        #pragma unroll
        for (int i = 0; i < 4; ++i)
            af2[i] = *(const bf16x8*)&sTt[(wave*64 + i*16 + l15)*TSTR + ks*32 + lk];
        #pragma unroll
        for (int j = 0; j < 6; ++j)
            bf2[j] = *(const bf16x8*)&AbG[(j*16 + l15)*NPGP + ks*32 + lk];
        #pragma unroll
        for (int i = 0; i < 4; ++i)
            #pragma unroll
            for (int j = 0; j < 6; ++j)
                acc2[i][j] = __builtin_amdgcn_mfma_f32_16x16x32_bf16(af2[i], bf2[j], acc2[i][j], 0, 0, 0);
    }
    // epilogue: bias + relu + store + column-sum partials (reg space = feat, l15 = d)
    f32x4 psum[4] = {};
    #pragma unroll
    for (int i = 0; i < 4; ++i) {
        int c0 = wave*64 + i*16 + q*4;
        float4 bv = *(const float4*)&bias[c0];
        #pragma unroll
        for (int j = 0; j < 6; ++j) {
            int d = j*16 + l15;
            if (d < NPG) {
                f32x4 v;
                v[0] = fmaxf(acc2[i][j][0] + bv.x, 0.f);
                v[1] = fmaxf(acc2[i][j][1] + bv.y, 0.f);
                v[2] = fmaxf(acc2[i][j][2] + bv.z, 0.f);
                v[3] = fmaxf(acc2[i][j][3] + bv.w, 0.f);
                ushort4 o;
                o.x = f2b(v[0]); o.y = f2b(v[1]); o.z = f2b(v[2]); o.w = f2b(v[3]);
                *(ushort4*)&eout[((size_t)g*NPG + d)*EMBD + c0] = o;
                psum[i] += v;
            }
        }
    }
    #pragma unroll
    for (int i = 0; i < 4; ++i) {
        #pragma unroll
        for (int r = 0; r < 4; ++r) {
            float s = psum[i][r];
            s += __shfl_xor(s, 1);
            s += __shfl_xor(s, 2);
            s += __shfl_xor(s, 4);
            s += __shfl_xor(s, 8);
            if (l15 == 0)
                gout[(size_t)g*EMBD + wave*64 + i*16 + q*4 + r] = s;
        }
    }
}

// ---- logits: one wave per graph ----
__global__ __launch_bounds__(64) void k_logits(const float* __restrict__ gsum,
                                               const float* __restrict__ Wc,
                                               const float* __restrict__ bc,
                                               float* __restrict__ outp) {
    int g = blockIdx.x, l = threadIdx.x;
    float p0 = 0.f, p1 = 0.f;
    #pragma unroll
    for (int k = 0; k < 12; ++k) {
        int c = k*64 + l;
        float v = gsum[(size_t)g*EMBD + c];
        p0 += v * Wc[c*2 + 0];
        p1 += v * Wc[c*2 + 1];
    }
    #pragma unroll
    for (int m = 32; m; m >>= 1) { p0 += __shfl_xor(p0, m); p1 += __shfl_xor(p1, m); }
    if (l == 0) {
        outp[ADJSZ + g*2 + 0] = p0*(1.0f/87.0f) + bc[0];
        outp[ADJSZ + g*2 + 1] = p1*(1.0f/87.0f) + bc[1];
    }
}

// ---- decoder: relu(ne @ ne^T) per graph via MFMA ----
#define ESTR 264
__global__ __launch_bounds__(256) void k_dec(const ushort* __restrict__ emb,
                                             float* __restrict__ outp) {
    __shared__ ushort sE[NPGP*ESTR];
    const int tid = threadIdx.x;
    const int wave = tid >> 6, lane = tid & 63;
    const int g = blockIdx.x;
    const int it0 = (wave >> 1)*3, jt0 = (wave & 1)*3;
    const int l15 = lane & 15, lk = (lane >> 4)*8;
    f32x4 acc[3][3] = {};
    for (int ch = 0; ch < 3; ++ch) {
        __syncthreads();
        #pragma unroll
        for (int it = 0; it < 12; ++it) {
            int flat = tid + it*256;           // over 96*32
            int r = flat >> 5, p = flat & 31;
            bf16x8 v = {};
            if (r < NPG)
                v = *(const bf16x8*)&emb[((size_t)g*NPG + r)*EMBD + ch*HID + p*8];
            *(bf16x8*)&sE[r*ESTR + p*8] = v;
        }
        __syncthreads();
        #pragma unroll
        for (int ks = 0; ks < 8; ++ks) {
            bf16x8 af[3], bfr[3];
            #pragma unroll
            for (int t = 0; t < 3; ++t) {
                af[t]  = *(const bf16x8*)&sE[((it0 + t)*16 + l15)*ESTR + ks*32 + lk];
                bfr[t] = *(const bf16x8*)&sE[((jt0 + t)*16 + l15)*ESTR + ks*32 + lk];
            }
            #pragma unroll
            for (int i = 0; i < 3; ++i)
                #pragma unroll
                for (int j = 0; j < 3; ++j)
                    acc[i][j] = __builtin_amdgcn_mfma_f32_16x16x32_bf16(af[i], bfr[j], acc[i][j], 0, 0, 0);
        }
    }
    const int rq = (lane >> 4)*4;
    #pragma unroll
    for (int i = 0; i < 3; ++i) {
        #pragma unroll
        for (int j = 0; j < 3; ++j) {
            int jj = (jt0 + j)*16 + l15;
            if (jj < NPG) {
                #pragma unroll
                for (int r = 0; r < 4; ++r) {
                    int ii = (it0 + i)*16 + rq + r;
                    if (ii < NPG)
                        outp[((size_t)g*NPG + ii)*NPG + jj] = fmaxf(acc[i][j][r], 0.f);
                }
            }
        }
    }
}

extern "C" void kernel_launch(void* const* d_in, const int* in_sizes, int n_in,
                              void* d_out, int out_size, void* d_ws, size_t ws_size,
                              hipStream_t stream) {
    const float* x   = (const float*)d_in[0];
    const int*   ei  = (const int*)d_in[1];
    const float* ew  = (const float*)d_in[2];
    const float* W1  = (const float*)d_in[4];
    const float* b1  = (const float*)d_in[5];
    const float* W2  = (const float*)d_in[6];
    const float* b2  = (const float*)d_in[7];
    const float* W3  = (const float*)d_in[8];
    const float* b3  = (const float*)d_in[9];
    const float* Wc  = (const float*)d_in[10];
    const float* bc  = (const float*)d_in[11];
    float* outp = (float*)d_out;

    char* ws = (char*)d_ws;
    ushort* Ab   = (ushort*)ws;  ws += (size_t)B_GRAPHS*NPGP*NPGP*2;
    ushort* WT1  = (ushort*)ws;  ws += (size_t)HID*NPGP*2;
    ushort* WT2  = (ushort*)ws;  ws += (size_t)HID*HID*2;
    ushort* WT3  = (ushort*)ws;  ws += (size_t)HID*HID*2;
    ushort* emb  = (ushort*)ws;  ws += (size_t)NN*EMBD*2;
    float*  gsum = (float*)ws;   ws += (size_t)B_GRAPHS*EMBD*4;

    const int* srcp = ei;
    const int* dstp = ei + NE;

    k_cast_wt<<<dim3(256,3), 256, 0, stream>>>(W1, W2, W3, WT1, WT2, WT3);
    k_buildA <<<B_GRAPHS, 256, 0, stream>>>(srcp, dstp, ew, Ab);

    k_layer<96> <<<B_GRAPHS, 256, 0, stream>>>(x, nullptr, WT1, b1, Ab, emb,       gsum);
    k_layer<256><<<B_GRAPHS, 256, 0, stream>>>(nullptr, emb,       WT2, b2, Ab, emb + 256, gsum + 256);
    k_layer<256><<<B_GRAPHS, 256, 0, stream>>>(nullptr, emb + 256, WT3, b3, Ab, emb + 512, gsum + 512);

    k_logits<<<B_GRAPHS, 64, 0, stream>>>(gsum, Wc, bc, outp);
    k_dec   <<<B_GRAPHS, 256, 0, stream>>>(emb, outp);
}

// Round 6
// 94.325 us; speedup vs baseline: 6.5561x; 1.3015x over previous
//
#include <hip/hip_runtime.h>

#define B_GRAPHS 512
#define NPG 87
#define NPGP 96
#define EPG 1392
#define NN (B_GRAPHS*NPG)        // 44544
#define NE (B_GRAPHS*EPG)        // 712704
#define HID 256
#define EMBD 768
#define ADJSZ (B_GRAPHS*NPG*NPG) // 3875328
#define HSTR 264                 // h layout stride (96 rows x 256 feats): 528B, 2-way banks (free)
#define TSTR 104                 // Tt layout stride (256 rows x 96 nodes): 208B, 2-way banks (free)
#define BUF_ELEMS 26624          // max(96*264=25336(+pad), 256*104=26624) ushorts = 53248 B

typedef __attribute__((ext_vector_type(8))) short bf16x8;
typedef __attribute__((ext_vector_type(4))) float f32x4;

__device__ __forceinline__ ushort f2b(float f) {
    uint u = __float_as_uint(f);
    return (ushort)((u + 0x7FFFu + ((u >> 16) & 1u)) >> 16);
}
__device__ __forceinline__ ushort4 cvt4(f32x4 v) {
    ushort4 o; o.x = f2b(v[0]); o.y = f2b(v[1]); o.z = f2b(v[2]); o.w = f2b(v[3]);
    return o;
}

// ---- W [K][256] f32 -> WT [256][Kp] bf16 (transposed, zero-padded) ----
__global__ __launch_bounds__(256) void k_cast_wt(const float* __restrict__ W1,
                                                 const float* __restrict__ W2,
                                                 const float* __restrict__ W3,
                                                 ushort* __restrict__ WT1,
                                                 ushort* __restrict__ WT2,
                                                 ushort* __restrict__ WT3) {
    int y = blockIdx.y;
    const float* W = (y == 0) ? W1 : (y == 1) ? W2 : W3;
    ushort* WT = (y == 0) ? WT1 : (y == 1) ? WT2 : WT3;
    int K  = (y == 0) ? NPG : HID;
    int Kp = (y == 0) ? NPGP : HID;
    int idx = blockIdx.x*256 + threadIdx.x;
    if (idx >= 256*Kp) return;
    int c = idx / Kp, k = idx - c*Kp;
    WT[idx] = (k < K) ? f2b(W[(size_t)k*HID + c]) : (ushort)0;
}

// ---- dense normalized adjacency Ab[g][d][s], bf16, 96x96 zero-padded ----
// DETERMINISTIC: integer fixed-point atomics (order-independent sums).
__global__ __launch_bounds__(256) void k_buildA(const int* __restrict__ src,
                                                const int* __restrict__ dst,
                                                const float* __restrict__ ew,
                                                ushort* __restrict__ Ab) {
    __shared__ int   sAi[NPGP*NPGP];   // A accum, scale 2^24
    __shared__ int   sdegi[NPGP];      // deg accum, scale 2^20
    __shared__ float sdi[NPGP];
    int g = blockIdx.x, tid = threadIdx.x;
    for (int i = tid; i < NPGP*NPGP; i += 256) sAi[i] = 0;
    if (tid < NPGP) sdegi[tid] = 0;
    int base = g*NPG;
    int sl[6], dl[6]; float wv[6];
    #pragma unroll
    for (int it = 0; it < 6; ++it) {
        int eo = tid + it*256;
        bool v = (eo < EPG);
        int e = g*EPG + (v ? eo : 0);
        sl[it] = src[e] - base;
        dl[it] = dst[e] - base;
        wv[it] = v ? ew[e] : 0.f;
    }
    __syncthreads();
    #pragma unroll
    for (int it = 0; it < 6; ++it)
        atomicAdd(&sdegi[dl[it]], (int)rintf(wv[it]*1048576.0f));
    __syncthreads();
    if (tid < NPGP) {
        float deg = 1.0f + (float)sdegi[tid]*(1.0f/1048576.0f);   // +1 self-loop
        sdi[tid] = rsqrtf(deg);
    }
    __syncthreads();
    #pragma unroll
    for (int it = 0; it < 6; ++it) {
        float v = sdi[sl[it]]*wv[it]*sdi[dl[it]];
        atomicAdd(&sAi[dl[it]*NPGP + sl[it]], (int)rintf(v*16777216.0f));
    }
    __syncthreads();
    ushort* outp = Ab + (size_t)g*NPGP*NPGP;
    for (int i = tid; i < NPGP*NPGP; i += 256) {
        int r = i / NPGP, c = i - r*NPGP;
        float a = (float)sAi[i]*(1.0f/16777216.0f);
        if (r == c && r < NPG) { float di = sdi[r]; a += di*di; }   // self-loop term
        outp[i] = f2b(a);
    }
}

// ---- mega kernel: one block per graph; 3 layers + pool partials + decoder fused ----
// Single 52KB LDS buffer, time-shared between h-layout [96][HSTR] and Tt-layout
// [256][TSTR]. Strict cycle per layer:
//   S1 read h        -> barrier a -> S2 write Tt (overwrite)
//   -> barrier b -> S3 read Tt    -> barrier c -> S4 write h (overwrite)
//   -> barrier d -> S5 gram reads h ... next layer S1 reads h (reads||reads ok;
//   next write is S2, protected by next barrier a).
__global__ __launch_bounds__(512, 4) void k_mega(const float* __restrict__ x,
                                                 const ushort* __restrict__ Ab,
                                                 const ushort* __restrict__ WT1,
                                                 const ushort* __restrict__ WT2,
                                                 const ushort* __restrict__ WT3,
                                                 const float* __restrict__ b1,
                                                 const float* __restrict__ b2,
                                                 const float* __restrict__ b3,
                                                 float* __restrict__ gsum,
                                                 float* __restrict__ outp) {
    __shared__ ushort buf[BUF_ELEMS];
    const int g = blockIdx.x, tid = threadIdx.x;
    const int wave = tid >> 6, lane = tid & 63;
    const int l15 = lane & 15, q = lane >> 4, lk = q*8;
    const int mg = wave >> 2, fg = wave & 3;

    // stage x into h-layout (rows 0..95 x cols 0..95, zero-padded)
    for (int idx = tid; idx < NPGP*NPGP; idx += 512) {
        int r = idx / NPGP, c = idx - r*NPGP;
        float v = (r < NPG && c < NPG) ? x[((size_t)g*NPG + r)*NPG + c] : 0.f;
        buf[r*HSTR + c] = f2b(v);
    }
    __syncthreads();

    const ushort* AbG = Ab + (size_t)g*NPGP*NPGP;
    float* gOut = gsum + (size_t)g*2*EMBD;
    f32x4 gacc[6] = {};

    for (int layer = 0; layer < 3; ++layer) {
        const ushort* WT  = (layer == 0) ? WT1 : (layer == 1) ? WT2 : WT3;
        const float* bias = (layer == 0) ? b1  : (layer == 1) ? b2  : b3;
        const int Kp  = (layer == 0) ? NPGP : HID;
        const int nks = Kp >> 5;

        // ---- S1: T = H @ W (read h from buf, WT from global) ----
        f32x4 acc1[3][4] = {};
        for (int ks = 0; ks < nks; ++ks) {
            bf16x8 af[3], bfr[4];
            #pragma unroll
            for (int i = 0; i < 3; ++i)
                af[i] = *(const bf16x8*)&buf[(mg*48 + i*16 + l15)*HSTR + ks*32 + lk];
            #pragma unroll
            for (int j = 0; j < 4; ++j)
                bfr[j] = *(const bf16x8*)&WT[(size_t)(fg*64 + j*16 + l15)*Kp + ks*32 + lk];
            #pragma unroll
            for (int i = 0; i < 3; ++i)
                #pragma unroll
                for (int j = 0; j < 4; ++j)
                    acc1[i][j] = __builtin_amdgcn_mfma_f32_16x16x32_bf16(af[i], bfr[j], acc1[i][j], 0, 0, 0);
        }
        __syncthreads();   // (a) all h reads (incl. previous gram) complete
        // ---- S2: write Tt[feat][node] over buf ----
        #pragma unroll
        for (int i = 0; i < 3; ++i)
            #pragma unroll
            for (int j = 0; j < 4; ++j)
                *(ushort4*)&buf[(fg*64 + j*16 + l15)*TSTR + mg*48 + i*16 + q*4] = cvt4(acc1[i][j]);
        __syncthreads();   // (b) Tt ready

        // ---- S3: E = A @ T (read Tt from buf, A from global) ----
        f32x4 acc2[4][3] = {};
        #pragma unroll
        for (int ks = 0; ks < 3; ++ks) {
            bf16x8 af2[4], bf2[3];
            #pragma unroll
            for (int i = 0; i < 4; ++i)
                af2[i] = *(const bf16x8*)&buf[(fg*64 + i*16 + l15)*TSTR + ks*32 + lk];
            #pragma unroll
            for (int j = 0; j < 3; ++j)
                bf2[j] = *(const bf16x8*)&AbG[(mg*48 + j*16 + l15)*NPGP + ks*32 + lk];
            #pragma unroll
            for (int i = 0; i < 4; ++i)
                #pragma unroll
                for (int j = 0; j < 3; ++j)
                    acc2[i][j] = __builtin_amdgcn_mfma_f32_16x16x32_bf16(af2[i], bf2[j], acc2[i][j], 0, 0, 0);
        }
        __syncthreads();   // (c) Tt reads complete

        // ---- S4: h = relu(E + b) over buf + pool partials ----
        const int loff = layer << 8;
        #pragma unroll
        for (int i = 0; i < 4; ++i) {
            int featb = fg*64 + i*16 + q*4;
            float4 bv = *(const float4*)&bias[featb];
            f32x4 psum = {};
            #pragma unroll
            for (int j = 0; j < 3; ++j) {
                int d = mg*48 + j*16 + l15;
                f32x4 v;
                v[0] = fmaxf(acc2[i][j][0] + bv.x, 0.f);
                v[1] = fmaxf(acc2[i][j][1] + bv.y, 0.f);
                v[2] = fmaxf(acc2[i][j][2] + bv.z, 0.f);
                v[3] = fmaxf(acc2[i][j][3] + bv.w, 0.f);
                if (d >= NPG) { v[0] = 0.f; v[1] = 0.f; v[2] = 0.f; v[3] = 0.f; }
                *(ushort4*)&buf[d*HSTR + featb] = cvt4(v);
                psum += v;
            }
            float s0 = psum[0], s1 = psum[1], s2 = psum[2], s3 = psum[3];
            #pragma unroll
            for (int m = 1; m < 16; m <<= 1) {
                s0 += __shfl_xor(s0, m); s1 += __shfl_xor(s1, m);
                s2 += __shfl_xor(s2, m); s3 += __shfl_xor(s3, m);
            }
            if (l15 == 0)
                *(float4*)&gOut[mg*EMBD + loff + featb] = make_float4(s0, s1, s2, s3);
        }
        __syncthreads();   // (d) h ready

        // ---- S5: Gram accumulate gacc[j] += h_tile(wave) @ h_tile(j)^T ----
        if (wave < 6) {
            #pragma unroll
            for (int ks = 0; ks < 8; ++ks) {
                bf16x8 a = *(const bf16x8*)&buf[(wave*16 + l15)*HSTR + ks*32 + lk];
                #pragma unroll
                for (int j = 0; j < 6; ++j) {
                    bf16x8 b = *(const bf16x8*)&buf[(j*16 + l15)*HSTR + ks*32 + lk];
                    gacc[j] = __builtin_amdgcn_mfma_f32_16x16x32_bf16(a, b, gacc[j], 0, 0, 0);
                }
            }
        }
        // next layer's S1 reads h concurrently with S5 (reads||reads, safe);
        // next overwrite is S2, protected by barrier (a).
    }

    // decoder output: relu(Gram)
    if (wave < 6) {
        #pragma unroll
        for (int j = 0; j < 6; ++j) {
            int jj = j*16 + l15;
            if (jj < NPG) {
                #pragma unroll
                for (int r = 0; r < 4; ++r) {
                    int ii = wave*16 + q*4 + r;
                    if (ii < NPG)
                        outp[((size_t)g*NPG + ii)*NPG + jj] = fmaxf(gacc[j][r], 0.f);
                }
            }
        }
    }
}

// ---- logits: one wave per graph ----
__global__ __launch_bounds__(64) void k_logits(const float* __restrict__ gsum,
                                               const float* __restrict__ Wc,
                                               const float* __restrict__ bc,
                                               float* __restrict__ outp) {
    int g = blockIdx.x, l = threadIdx.x;
    float p0 = 0.f, p1 = 0.f;
    #pragma unroll
    for (int k = 0; k < 12; ++k) {
        int c = k*64 + l;
        float v = gsum[((size_t)g*2)*EMBD + c] + gsum[((size_t)g*2 + 1)*EMBD + c];
        p0 += v * Wc[c*2 + 0];
        p1 += v * Wc[c*2 + 1];
    }
    #pragma unroll
    for (int m = 32; m; m >>= 1) { p0 += __shfl_xor(p0, m); p1 += __shfl_xor(p1, m); }
    if (l == 0) {
        outp[ADJSZ + g*2 + 0] = p0*(1.0f/87.0f) + bc[0];
        outp[ADJSZ + g*2 + 1] = p1*(1.0f/87.0f) + bc[1];
    }
}

extern "C" void kernel_launch(void* const* d_in, const int* in_sizes, int n_in,
                              void* d_out, int out_size, void* d_ws, size_t ws_size,
                              hipStream_t stream) {
    const float* x   = (const float*)d_in[0];
    const int*   ei  = (const int*)d_in[1];
    const float* ew  = (const float*)d_in[2];
    const float* W1  = (const float*)d_in[4];
    const float* b1  = (const float*)d_in[5];
    const float* W2  = (const float*)d_in[6];
    const float* b2  = (const float*)d_in[7];
    const float* W3  = (const float*)d_in[8];
    const float* b3  = (const float*)d_in[9];
    const float* Wc  = (const float*)d_in[10];
    const float* bc  = (const float*)d_in[11];
    float* outp = (float*)d_out;

    char* ws = (char*)d_ws;
    ushort* Ab   = (ushort*)ws;  ws += (size_t)B_GRAPHS*NPGP*NPGP*2;
    ushort* WT1  = (ushort*)ws;  ws += (size_t)HID*NPGP*2;
    ushort* WT2  = (ushort*)ws;  ws += (size_t)HID*HID*2;
    ushort* WT3  = (ushort*)ws;  ws += (size_t)HID*HID*2;
    float*  gsum = (float*)ws;   ws += (size_t)B_GRAPHS*2*EMBD*4;

    const int* srcp = ei;
    const int* dstp = ei + NE;

    k_cast_wt<<<dim3(256,3), 256, 0, stream>>>(W1, W2, W3, WT1, WT2, WT3);
    k_buildA <<<B_GRAPHS, 256, 0, stream>>>(srcp, dstp, ew, Ab);
    k_mega   <<<B_GRAPHS, 512, 0, stream>>>(x, Ab, WT1, WT2, WT3, b1, b2, b3, gsum, outp);
    k_logits <<<B_GRAPHS, 64, 0, stream>>>(gsum, Wc, bc, outp);
}

// Round 7
// 84.627 us; speedup vs baseline: 7.3074x; 1.1146x over previous
//
#include <hip/hip_runtime.h>

#define B_GRAPHS 512
#define NPG 87
#define NPGP 96
#define EPG 1392
#define NN (B_GRAPHS*NPG)        // 44544
#define NE (B_GRAPHS*EPG)        // 712704
#define HID 256
#define EMBD 768
#define ADJSZ (B_GRAPHS*NPG*NPG) // 3875328
#define HSTR 264                 // h layout stride (96 rows x 256 feats): 528B, bank-spread
#define TSTR 104                 // Tt layout stride (256 rows x 96 nodes): 208B, bank-spread
#define ASTRF 92                 // adj f32 staging stride (rows 4 apart land 16 banks apart)
#define BUF_ELEMS 26624          // max(96*HSTR, 256*TSTR) ushorts = 53248 B

typedef __attribute__((ext_vector_type(8))) short bf16x8;
typedef __attribute__((ext_vector_type(4))) float f32x4;

__device__ __forceinline__ ushort f2b(float f) {
    uint u = __float_as_uint(f);
    return (ushort)((u + 0x7FFFu + ((u >> 16) & 1u)) >> 16);
}
__device__ __forceinline__ ushort4 cvt4(f32x4 v) {
    ushort4 o; o.x = f2b(v[0]); o.y = f2b(v[1]); o.z = f2b(v[2]); o.w = f2b(v[3]);
    return o;
}

// ---- W [K][256] f32 -> WTs in wave-fragment order ----
// Consumer (S1): lane reads bf16x8 at (((fg*NKS+ks)*4 + j)*64 + lane)*8,
// holding W^T[row=fg*64+j*16+(lane&15)][k=ks*32+(lane>>4)*8 + 0..7].
__global__ __launch_bounds__(256) void k_cast_wt(const float* __restrict__ W1,
                                                 const float* __restrict__ W2,
                                                 const float* __restrict__ W3,
                                                 ushort* __restrict__ WTs1,
                                                 ushort* __restrict__ WTs2,
                                                 ushort* __restrict__ WTs3) {
    int y = blockIdx.y;
    const float* W = (y == 0) ? W1 : (y == 1) ? W2 : W3;
    ushort* WTs = (y == 0) ? WTs1 : (y == 1) ? WTs2 : WTs3;
    int K   = (y == 0) ? NPG : HID;
    int NKS = (y == 0) ? 3 : 8;
    int total = 4*NKS*4*64*8;                 // 256*Kp
    int idx = blockIdx.x*256 + threadIdx.x;
    if (idx >= total) return;
    int e    = idx & 7;
    int lane = (idx >> 3) & 63;
    int j    = (idx >> 9) & 3;
    int rest = idx >> 11;
    int ks   = rest % NKS;
    int fg   = rest / NKS;
    int row = fg*64 + j*16 + (lane & 15);     // 0..255
    int k   = ks*32 + (lane >> 4)*8 + e;      // 0..Kp-1
    WTs[idx] = (k < K) ? f2b(W[(size_t)k*HID + row]) : (ushort)0;
}

// ---- dense normalized adjacency, wave-fragment order, deterministic int accum ----
// Consumer (S3): lane reads bf16x8 at (((mg*3+ks)*3 + j)*64 + lane)*8 holding
// A[d=mg*48+j*16+(lane&15)][s=ks*32+(lane>>4)*8 + 0..7].
__global__ __launch_bounds__(256) void k_buildA(const int* __restrict__ src,
                                                const int* __restrict__ dst,
                                                const float* __restrict__ ew,
                                                ushort* __restrict__ AbS) {
    __shared__ int   sAi[NPGP*NPGP];   // A accum, scale 2^24
    __shared__ int   sdegi[NPGP];      // deg accum, scale 2^20
    __shared__ float sdi[NPGP];
    int g = blockIdx.x, tid = threadIdx.x;
    for (int i = tid; i < NPGP*NPGP; i += 256) sAi[i] = 0;
    if (tid < NPGP) sdegi[tid] = 0;
    int base = g*NPG;
    int sl[6], dl[6]; float wv[6];
    #pragma unroll
    for (int it = 0; it < 6; ++it) {
        int eo = tid + it*256;
        bool v = (eo < EPG);
        int e = g*EPG + (v ? eo : 0);
        sl[it] = src[e] - base;
        dl[it] = dst[e] - base;
        wv[it] = v ? ew[e] : 0.f;
    }
    __syncthreads();
    #pragma unroll
    for (int it = 0; it < 6; ++it)
        atomicAdd(&sdegi[dl[it]], (int)rintf(wv[it]*1048576.0f));
    __syncthreads();
    if (tid < NPGP) {
        float deg = 1.0f + (float)sdegi[tid]*(1.0f/1048576.0f);   // +1 self-loop
        sdi[tid] = rsqrtf(deg);
    }
    __syncthreads();
    #pragma unroll
    for (int it = 0; it < 6; ++it) {
        float v = sdi[sl[it]]*wv[it]*sdi[dl[it]];
        atomicAdd(&sAi[dl[it]*NPGP + sl[it]], (int)rintf(v*16777216.0f));
    }
    __syncthreads();
    if (tid < NPG) {                   // diagonal self-loop term (single writer)
        float di = sdi[tid];
        sAi[tid*NPGP + tid] += (int)rintf(di*di*16777216.0f);
    }
    __syncthreads();
    ushort* outp = AbS + (size_t)g*NPGP*NPGP;
    for (int i = tid; i < NPGP*NPGP; i += 256) {
        int e    = i & 7;
        int lane = (i >> 3) & 63;
        int t    = i >> 9;             // 0..17
        int j  = t % 3;
        int ks = (t / 3) % 3;
        int mg = t / 9;
        int row = mg*48 + j*16 + (lane & 15);
        int col = ks*32 + (lane >> 4)*8 + e;
        outp[i] = f2b((float)sAi[row*NPGP + col]*(1.0f/16777216.0f));
    }
}

// ---- one GCN layer, fully LDS-resident, wave-fragment operand streams ----
template<int NKS>
__device__ __forceinline__ void do_layer(ushort* buf,
                                         const ushort* __restrict__ WTs,
                                         const float* __restrict__ bias,
                                         const ushort* __restrict__ AbG,
                                         float* __restrict__ sPool,
                                         f32x4 (&gacc)[6],
                                         int layer, int wave, int lane) {
    const int l15 = lane & 15, q = lane >> 4, lk = q*8;
    const int mg = wave >> 2, fg = wave & 3;

    // ---- S1: T = H @ W ----
    f32x4 acc1[3][4] = {};
    #pragma unroll
    for (int ks = 0; ks < NKS; ++ks) {
        bf16x8 af[3], bfr[4];
        #pragma unroll
        for (int i = 0; i < 3; ++i)
            af[i] = *(const bf16x8*)&buf[(mg*48 + i*16 + l15)*HSTR + ks*32 + lk];
        #pragma unroll
        for (int j = 0; j < 4; ++j)
            bfr[j] = *(const bf16x8*)&WTs[(size_t)(((fg*NKS + ks)*4 + j)*64 + lane)*8];
        #pragma unroll
        for (int i = 0; i < 3; ++i)
            #pragma unroll
            for (int j = 0; j < 4; ++j)
                acc1[i][j] = __builtin_amdgcn_mfma_f32_16x16x32_bf16(af[i], bfr[j], acc1[i][j], 0, 0, 0);
    }
    __syncthreads();   // (a) all h reads complete
    // ---- S2: write Tt[feat][node] over buf ----
    #pragma unroll
    for (int i = 0; i < 3; ++i)
        #pragma unroll
        for (int j = 0; j < 4; ++j)
            *(ushort4*)&buf[(fg*64 + j*16 + l15)*TSTR + mg*48 + i*16 + q*4] = cvt4(acc1[i][j]);
    __syncthreads();   // (b) Tt ready

    // ---- S3: E = A @ T ----
    f32x4 acc2[4][3] = {};
    #pragma unroll
    for (int ks = 0; ks < 3; ++ks) {
        bf16x8 af2[4], bf2[3];
        #pragma unroll
        for (int i = 0; i < 4; ++i)
            af2[i] = *(const bf16x8*)&buf[(fg*64 + i*16 + l15)*TSTR + ks*32 + lk];
        #pragma unroll
        for (int j = 0; j < 3; ++j)
            bf2[j] = *(const bf16x8*)&AbG[(((mg*3 + ks)*3 + j)*64 + lane)*8];
        #pragma unroll
        for (int i = 0; i < 4; ++i)
            #pragma unroll
            for (int j = 0; j < 3; ++j)
                acc2[i][j] = __builtin_amdgcn_mfma_f32_16x16x32_bf16(af2[i], bf2[j], acc2[i][j], 0, 0, 0);
    }
    __syncthreads();   // (c) Tt reads complete

    // ---- S4: h = relu(E + b) over buf + pool partials into sPool ----
    const int loff = layer << 8;
    #pragma unroll
    for (int i = 0; i < 4; ++i) {
        int featb = fg*64 + i*16 + q*4;
        float4 bv = *(const float4*)&bias[featb];
        f32x4 psum = {};
        #pragma unroll
        for (int j = 0; j < 3; ++j) {
            int d = mg*48 + j*16 + l15;
            f32x4 v;
            v[0] = fmaxf(acc2[i][j][0] + bv.x, 0.f);
            v[1] = fmaxf(acc2[i][j][1] + bv.y, 0.f);
            v[2] = fmaxf(acc2[i][j][2] + bv.z, 0.f);
            v[3] = fmaxf(acc2[i][j][3] + bv.w, 0.f);
            if (d >= NPG) { v[0] = 0.f; v[1] = 0.f; v[2] = 0.f; v[3] = 0.f; }
            *(ushort4*)&buf[d*HSTR + featb] = cvt4(v);
            psum += v;
        }
        float s0 = psum[0], s1 = psum[1], s2 = psum[2], s3 = psum[3];
        #pragma unroll
        for (int m = 1; m < 16; m <<= 1) {
            s0 += __shfl_xor(s0, m); s1 += __shfl_xor(s1, m);
            s2 += __shfl_xor(s2, m); s3 += __shfl_xor(s3, m);
        }
        if (l15 == 0)
            *(float4*)&sPool[mg*EMBD + loff + featb] = make_float4(s0, s1, s2, s3);
    }
    __syncthreads();   // (d) h ready

    // ---- S5: Gram accumulate gacc[j] += h_tile(wave) @ h_tile(j)^T ----
    if (wave < 6) {
        #pragma unroll
        for (int ks = 0; ks < 8; ++ks) {
            bf16x8 a = *(const bf16x8*)&buf[(wave*16 + l15)*HSTR + ks*32 + lk];
            #pragma unroll
            for (int j = 0; j < 6; ++j) {
                bf16x8 b = *(const bf16x8*)&buf[(j*16 + l15)*HSTR + ks*32 + lk];
                gacc[j] = __builtin_amdgcn_mfma_f32_16x16x32_bf16(a, b, gacc[j], 0, 0, 0);
            }
        }
    }
    // next layer's S1 reads h concurrently with S5 (reads||reads); next write
    // is S2, protected by its barrier (a).
}

// ---- mega kernel: 3 layers + pool + logits + decoder, one block per graph ----
__global__ __launch_bounds__(512, 4) void k_mega(const float* __restrict__ x,
                                                 const ushort* __restrict__ AbS,
                                                 const ushort* __restrict__ WTs1,
                                                 const ushort* __restrict__ WTs2,
                                                 const ushort* __restrict__ WTs3,
                                                 const float* __restrict__ b1,
                                                 const float* __restrict__ b2,
                                                 const float* __restrict__ b3,
                                                 const float* __restrict__ Wc,
                                                 const float* __restrict__ bc,
                                                 float* __restrict__ outp) {
    __shared__ ushort buf[BUF_ELEMS];
    __shared__ float  sPool[2*EMBD];
    const int g = blockIdx.x, tid = threadIdx.x;
    const int wave = tid >> 6, lane = tid & 63;
    const int l15 = lane & 15, q = lane >> 4;

    // stage x into h-layout (rows 0..95 x cols 0..95, zero-padded)
    for (int idx = tid; idx < NPGP*NPGP; idx += 512) {
        int r = idx / NPGP, c = idx - r*NPGP;
        float v = (r < NPG && c < NPG) ? x[((size_t)g*NPG + r)*NPG + c] : 0.f;
        buf[r*HSTR + c] = f2b(v);
    }
    __syncthreads();

    const ushort* AbG = AbS + (size_t)g*NPGP*NPGP;
    f32x4 gacc[6] = {};

    do_layer<3>(buf, WTs1, b1, AbG, sPool, gacc, 0, wave, lane);
    do_layer<8>(buf, WTs2, b2, AbG, sPool, gacc, 1, wave, lane);
    do_layer<8>(buf, WTs3, b3, AbG, sPool, gacc, 2, wave, lane);

    // ---- epilogue ----
    __syncthreads();                       // all Gram reads of buf complete
    float* fbuf = (float*)buf;             // adj staging [87][ASTRF] + reduce scratch
    if (wave < 6) {
        #pragma unroll
        for (int j = 0; j < 6; ++j) {
            int jj = j*16 + l15;
            #pragma unroll
            for (int r = 0; r < 4; ++r) {
                int ii = wave*16 + q*4 + r;
                if (jj < NPG && ii < NPG)
                    fbuf[ii*ASTRF + jj] = fmaxf(gacc[j][r], 0.f);
            }
        }
    }
    // logits partials (sPool complete as of barrier (d) of layer 3)
    float p0 = 0.f, p1 = 0.f;
    #pragma unroll
    for (int k2 = 0; k2 < 3; ++k2) {
        int c = tid + k2*512;
        int f = (c >= EMBD) ? c - EMBD : c;
        float v = sPool[c];
        p0 += v * Wc[f*2 + 0];
        p1 += v * Wc[f*2 + 1];
    }
    #pragma unroll
    for (int m = 1; m < 64; m <<= 1) { p0 += __shfl_xor(p0, m); p1 += __shfl_xor(p1, m); }
    if (lane == 0) { fbuf[8064 + wave*2] = p0; fbuf[8064 + wave*2 + 1] = p1; }
    __syncthreads();

    // coalesced adj copy-out (30.3 KB contiguous per graph)
    float* og = outp + (size_t)g*NPG*NPG;
    for (int idx = tid; idx < NPG*NPG; idx += 512) {
        int r = idx / NPG, cc = idx - r*NPG;
        og[idx] = fbuf[r*ASTRF + cc];
    }
    if (tid == 0) {
        float q0 = 0.f, q1 = 0.f;
        #pragma unroll
        for (int w = 0; w < 8; ++w) { q0 += fbuf[8064 + w*2]; q1 += fbuf[8064 + w*2 + 1]; }
        outp[ADJSZ + (size_t)g*2 + 0] = q0*(1.0f/87.0f) + bc[0];
        outp[ADJSZ + (size_t)g*2 + 1] = q1*(1.0f/87.0f) + bc[1];
    }
}

extern "C" void kernel_launch(void* const* d_in, const int* in_sizes, int n_in,
                              void* d_out, int out_size, void* d_ws, size_t ws_size,
                              hipStream_t stream) {
    const float* x   = (const float*)d_in[0];
    const int*   ei  = (const int*)d_in[1];
    const float* ew  = (const float*)d_in[2];
    const float* W1  = (const float*)d_in[4];
    const float* b1  = (const float*)d_in[5];
    const float* W2  = (const float*)d_in[6];
    const float* b2  = (const float*)d_in[7];
    const float* W3  = (const float*)d_in[8];
    const float* b3  = (const float*)d_in[9];
    const float* Wc  = (const float*)d_in[10];
    const float* bc  = (const float*)d_in[11];
    float* outp = (float*)d_out;

    char* ws = (char*)d_ws;
    ushort* AbS  = (ushort*)ws;  ws += (size_t)B_GRAPHS*NPGP*NPGP*2;
    ushort* WTs1 = (ushort*)ws;  ws += (size_t)HID*NPGP*2;
    ushort* WTs2 = (ushort*)ws;  ws += (size_t)HID*HID*2;
    ushort* WTs3 = (ushort*)ws;  ws += (size_t)HID*HID*2;

    const int* srcp = ei;
    const int* dstp = ei + NE;

    k_cast_wt<<<dim3(256,3), 256, 0, stream>>>(W1, W2, W3, WTs1, WTs2, WTs3);
    k_buildA <<<B_GRAPHS, 256, 0, stream>>>(srcp, dstp, ew, AbS);
    k_mega   <<<B_GRAPHS, 512, 0, stream>>>(x, AbS, WTs1, WTs2, WTs3,
                                            b1, b2, b3, Wc, bc, outp);
}

// Round 9
// 71.211 us; speedup vs baseline: 8.6841x; 1.1884x over previous
//
#include <hip/hip_runtime.h>
#include <hip/hip_bf16.h>

#define B_GRAPHS 512
#define NPG 87
#define NPGP 96
#define EPG 1392
#define NN (B_GRAPHS*NPG)        // 44544
#define NE (B_GRAPHS*EPG)        // 712704
#define HID 256
#define EMBD 768
#define ADJSZ (B_GRAPHS*NPG*NPG) // 3875328
#define HSTR 264                 // h layout stride (96 rows x 256 feats)
#define TSTR 104                 // Tt layout stride (256 rows x 96 nodes)
#define ASTRF 92                 // adj f32 staging stride
#define BUF_ELEMS 26624          // max(96*HSTR, 256*TSTR) ushorts = 53248 B

typedef __attribute__((ext_vector_type(8))) short bf16x8;
typedef __attribute__((ext_vector_type(4))) float f32x4;

// native f32->bf16 (RNE); compiler pairs adjacent casts into v_cvt_pk_bf16_f32
__device__ __forceinline__ ushort f2b(float f) {
    __hip_bfloat16 h = __float2bfloat16(f);
    ushort u;
    __builtin_memcpy(&u, &h, 2);
    return u;
}
__device__ __forceinline__ ushort4 cvt4(f32x4 v) {
    ushort4 o; o.x = f2b(v[0]); o.y = f2b(v[1]); o.z = f2b(v[2]); o.w = f2b(v[3]);
    return o;
}

// upper-triangle tile rank t in [0,21) -> (i,j), i<=j<6
__device__ __forceinline__ void unrank21(int t, int& i, int& j) {
    i = (t >= 20) ? 5 : (t >= 18) ? 4 : (t >= 15) ? 3 : (t >= 11) ? 2 : (t >= 6) ? 1 : 0;
    int off = (i == 5) ? 20 : (i == 4) ? 18 : (i == 3) ? 15 : (i == 2) ? 11 : (i == 1) ? 6 : 0;
    j = i + (t - off);
}

// ---- W [K][256] f32 -> WTs in wave-fragment order ----
__global__ __launch_bounds__(256) void k_cast_wt(const float* __restrict__ W1,
                                                 const float* __restrict__ W2,
                                                 const float* __restrict__ W3,
                                                 ushort* __restrict__ WTs1,
                                                 ushort* __restrict__ WTs2,
                                                 ushort* __restrict__ WTs3) {
    int y = blockIdx.y;
    const float* W = (y == 0) ? W1 : (y == 1) ? W2 : W3;
    ushort* WTs = (y == 0) ? WTs1 : (y == 1) ? WTs2 : WTs3;
    int K   = (y == 0) ? NPG : HID;
    int NKS = (y == 0) ? 3 : 8;
    int total = 4*NKS*4*64*8;                 // 256*Kp
    int idx = blockIdx.x*256 + threadIdx.x;
    if (idx >= total) return;
    int e    = idx & 7;
    int lane = (idx >> 3) & 63;
    int j    = (idx >> 9) & 3;
    int rest = idx >> 11;
    int ks   = rest % NKS;
    int fg   = rest / NKS;
    int row = fg*64 + j*16 + (lane & 15);     // 0..255
    int k   = ks*32 + (lane >> 4)*8 + e;      // 0..Kp-1
    WTs[idx] = (k < K) ? f2b(W[(size_t)k*HID + row]) : (ushort)0;
}

// ---- dense normalized adjacency, wave-fragment order, deterministic int accum ----
__global__ __launch_bounds__(256) void k_buildA(const int* __restrict__ src,
                                                const int* __restrict__ dst,
                                                const float* __restrict__ ew,
                                                ushort* __restrict__ AbS) {
    __shared__ int   sAi[NPGP*NPGP];   // A accum, scale 2^24
    __shared__ int   sdegi[NPGP];      // deg accum, scale 2^20
    __shared__ float sdi[NPGP];
    int g = blockIdx.x, tid = threadIdx.x;
    for (int i = tid; i < NPGP*NPGP; i += 256) sAi[i] = 0;
    if (tid < NPGP) sdegi[tid] = 0;
    int base = g*NPG;
    int sl[6], dl[6]; float wv[6];
    #pragma unroll
    for (int it = 0; it < 6; ++it) {
        int eo = tid + it*256;
        bool v = (eo < EPG);
        int e = g*EPG + (v ? eo : 0);
        sl[it] = src[e] - base;
        dl[it] = dst[e] - base;
        wv[it] = v ? ew[e] : 0.f;
    }
    __syncthreads();
    #pragma unroll
    for (int it = 0; it < 6; ++it)
        atomicAdd(&sdegi[dl[it]], (int)rintf(wv[it]*1048576.0f));
    __syncthreads();
    if (tid < NPGP) {
        float deg = 1.0f + (float)sdegi[tid]*(1.0f/1048576.0f);   // +1 self-loop
        sdi[tid] = rsqrtf(deg);
    }
    __syncthreads();
    #pragma unroll
    for (int it = 0; it < 6; ++it) {
        float v = sdi[sl[it]]*wv[it]*sdi[dl[it]];
        atomicAdd(&sAi[dl[it]*NPGP + sl[it]], (int)rintf(v*16777216.0f));
    }
    __syncthreads();
    if (tid < NPG) {                   // diagonal self-loop term (single writer)
        float di = sdi[tid];
        sAi[tid*NPGP + tid] += (int)rintf(di*di*16777216.0f);
    }
    __syncthreads();
    ushort* outp = AbS + (size_t)g*NPGP*NPGP;
    for (int i = tid; i < NPGP*NPGP; i += 256) {
        int e    = i & 7;
        int lane = (i >> 3) & 63;
        int t    = i >> 9;             // 0..17
        int j  = t % 3;
        int ks = (t / 3) % 3;
        int mg = t / 9;
        int row = mg*48 + j*16 + (lane & 15);
        int col = ks*32 + (lane >> 4)*8 + e;
        outp[i] = f2b((float)sAi[row*NPGP + col]*(1.0f/16777216.0f));
    }
}

// ---- one GCN layer, fully LDS-resident ----
template<int NKS>
__device__ __forceinline__ void do_layer(ushort* buf,
                                         const ushort* __restrict__ WTs,
                                         const float* __restrict__ bias,
                                         const ushort* __restrict__ AbG,
                                         float* __restrict__ sPool,
                                         int layer, int wave, int lane) {
    const int l15 = lane & 15, q = lane >> 4, lk = q*8;
    const int mg = wave >> 2, fg = wave & 3;

    // ---- S1: T = H @ W ----
    f32x4 acc1[3][4] = {};
    #pragma unroll
    for (int ks = 0; ks < NKS; ++ks) {
        bf16x8 af[3], bfr[4];
        #pragma unroll
        for (int i = 0; i < 3; ++i)
            af[i] = *(const bf16x8*)&buf[(mg*48 + i*16 + l15)*HSTR + ks*32 + lk];
        #pragma unroll
        for (int j = 0; j < 4; ++j)
            bfr[j] = *(const bf16x8*)&WTs[(size_t)(((fg*NKS + ks)*4 + j)*64 + lane)*8];
        #pragma unroll
        for (int i = 0; i < 3; ++i)
            #pragma unroll
            for (int j = 0; j < 4; ++j)
                acc1[i][j] = __builtin_amdgcn_mfma_f32_16x16x32_bf16(af[i], bfr[j], acc1[i][j], 0, 0, 0);
    }
    __syncthreads();   // (a) all h reads complete
    // ---- S2: write Tt[feat][node] over buf ----
    #pragma unroll
    for (int i = 0; i < 3; ++i)
        #pragma unroll
        for (int j = 0; j < 4; ++j)
            *(ushort4*)&buf[(fg*64 + j*16 + l15)*TSTR + mg*48 + i*16 + q*4] = cvt4(acc1[i][j]);
    __syncthreads();   // (b) Tt ready

    // ---- S3: E = A @ T ----
    f32x4 acc2[4][3] = {};
    #pragma unroll
    for (int ks = 0; ks < 3; ++ks) {
        bf16x8 af2[4], bf2[3];
        #pragma unroll
        for (int i = 0; i < 4; ++i)
            af2[i] = *(const bf16x8*)&buf[(fg*64 + i*16 + l15)*TSTR + ks*32 + lk];
        #pragma unroll
        for (int j = 0; j < 3; ++j)
            bf2[j] = *(const bf16x8*)&AbG[(((mg*3 + ks)*3 + j)*64 + lane)*8];
        #pragma unroll
        for (int i = 0; i < 4; ++i)
            #pragma unroll
            for (int j = 0; j < 3; ++j)
                acc2[i][j] = __builtin_amdgcn_mfma_f32_16x16x32_bf16(af2[i], bf2[j], acc2[i][j], 0, 0, 0);
    }
    __syncthreads();   // (c) Tt reads complete

    // ---- S4: h = relu(E + b) over buf + pool partials into sPool ----
    const int loff = layer << 8;
    #pragma unroll
    for (int i = 0; i < 4; ++i) {
        int featb = fg*64 + i*16 + q*4;
        float4 bv = *(const float4*)&bias[featb];
        f32x4 psum = {};
        #pragma unroll
        for (int j = 0; j < 3; ++j) {
            int d = mg*48 + j*16 + l15;
            f32x4 v;
            v[0] = fmaxf(acc2[i][j][0] + bv.x, 0.f);
            v[1] = fmaxf(acc2[i][j][1] + bv.y, 0.f);
            v[2] = fmaxf(acc2[i][j][2] + bv.z, 0.f);
            v[3] = fmaxf(acc2[i][j][3] + bv.w, 0.f);
            if (d >= NPG) { v[0] = 0.f; v[1] = 0.f; v[2] = 0.f; v[3] = 0.f; }
            *(ushort4*)&buf[d*HSTR + featb] = cvt4(v);
            psum += v;
        }
        float s0 = psum[0], s1 = psum[1], s2 = psum[2], s3 = psum[3];
        #pragma unroll
        for (int m = 1; m < 16; m <<= 1) {
            s0 += __shfl_xor(s0, m); s1 += __shfl_xor(s1, m);
            s2 += __shfl_xor(s2, m); s3 += __shfl_xor(s3, m);
        }
        if (l15 == 0)
            *(float4*)&sPool[mg*EMBD + loff + featb] = make_float4(s0, s1, s2, s3);
    }
    __syncthreads();   // (d) h ready (Gram + next S1 read after this)
}

// ---- symmetric Gram: 21 upper-triangle tiles, consecutive ranges per wave ----
// waves 0..4 own t in [3w, 3w+3); waves 5..7 own t in [15+2(w-5), +2)
__device__ __forceinline__ void do_gram(const ushort* buf, int wave, int lane,
                                        f32x4 (&gacc)[3]) {
    const int l15 = lane & 15, lk = (lane >> 4)*8;
    const int start = (wave < 5) ? wave*3 : 15 + (wave - 5)*2;
    const int count = (wave < 5) ? 3 : 2;
    int ra0, rb0, ra1, rb1, ra2, rb2;
    unrank21(start,     ra0, rb0);
    unrank21(start + 1, ra1, rb1);
    unrank21(count > 2 ? start + 2 : start, ra2, rb2);  // dummy=slot0 if unused
    #pragma unroll
    for (int ks = 0; ks < 8; ++ks) {
        bf16x8 a0 = *(const bf16x8*)&buf[(ra0*16 + l15)*HSTR + ks*32 + lk];
        bf16x8 b0 = *(const bf16x8*)&buf[(rb0*16 + l15)*HSTR + ks*32 + lk];
        gacc[0] = __builtin_amdgcn_mfma_f32_16x16x32_bf16(a0, b0, gacc[0], 0, 0, 0);
        bf16x8 a1 = *(const bf16x8*)&buf[(ra1*16 + l15)*HSTR + ks*32 + lk];
        bf16x8 b1 = *(const bf16x8*)&buf[(rb1*16 + l15)*HSTR + ks*32 + lk];
        gacc[1] = __builtin_amdgcn_mfma_f32_16x16x32_bf16(a1, b1, gacc[1], 0, 0, 0);
        if (count > 2) {
            bf16x8 a2 = *(const bf16x8*)&buf[(ra2*16 + l15)*HSTR + ks*32 + lk];
            bf16x8 b2 = *(const bf16x8*)&buf[(rb2*16 + l15)*HSTR + ks*32 + lk];
            gacc[2] = __builtin_amdgcn_mfma_f32_16x16x32_bf16(a2, b2, gacc[2], 0, 0, 0);
        }
    }
}

// ---- mega kernel: 3 layers + pool + logits + decoder, one block per graph ----
__global__ __launch_bounds__(512, 4) void k_mega(const float* __restrict__ x,
                                                 const ushort* __restrict__ AbS,
                                                 const ushort* __restrict__ WTs1,
                                                 const ushort* __restrict__ WTs2,
                                                 const ushort* __restrict__ WTs3,
                                                 const float* __restrict__ b1,
                                                 const float* __restrict__ b2,
                                                 const float* __restrict__ b3,
                                                 const float* __restrict__ Wc,
                                                 const float* __restrict__ bc,
                                                 float* __restrict__ outp) {
    __shared__ ushort buf[BUF_ELEMS];
    __shared__ float  sPool[2*EMBD];
    const int g = blockIdx.x, tid = threadIdx.x;
    const int wave = tid >> 6, lane = tid & 63;
    const int l15 = lane & 15, q = lane >> 4;

    // stage x into h-layout (rows 0..95 x cols 0..95, zero-padded)
    for (int idx = tid; idx < NPGP*NPGP; idx += 512) {
        int r = idx / NPGP, c = idx - r*NPGP;
        float v = (r < NPG && c < NPG) ? x[((size_t)g*NPG + r)*NPG + c] : 0.f;
        buf[r*HSTR + c] = f2b(v);
    }
    __syncthreads();

    const ushort* AbG = AbS + (size_t)g*NPGP*NPGP;
    f32x4 gacc[3] = {};

    do_layer<3>(buf, WTs1, b1, AbG, sPool, 0, wave, lane);
    do_gram(buf, wave, lane, gacc);
    do_layer<8>(buf, WTs2, b2, AbG, sPool, 1, wave, lane);
    do_gram(buf, wave, lane, gacc);
    do_layer<8>(buf, WTs3, b3, AbG, sPool, 2, wave, lane);
    do_gram(buf, wave, lane, gacc);

    // ---- epilogue ----
    __syncthreads();                       // all Gram/S1 reads of buf complete
    float* fbuf = (float*)buf;             // adj staging [87][ASTRF] + reduce scratch
    {
        const int start = (wave < 5) ? wave*3 : 15 + (wave - 5)*2;
        const int count = (wave < 5) ? 3 : 2;
        #pragma unroll
        for (int s = 0; s < 3; ++s) {
            if (s < count) {
                int ti, tj;
                unrank21(start + s, ti, tj);
                int jj = tj*16 + l15;
                #pragma unroll
                for (int r = 0; r < 4; ++r) {
                    int ii = ti*16 + q*4 + r;
                    float v = fmaxf(gacc[s][r], 0.f);
                    if (ii < NPG && jj < NPG) {
                        fbuf[ii*ASTRF + jj] = v;
                        if (ti != tj) fbuf[jj*ASTRF + ii] = v;
                    }
                }
            }
        }
    }
    // logits partials (sPool stable since layer-3 barrier (d))
    float p0 = 0.f, p1 = 0.f;
    #pragma unroll
    for (int k2 = 0; k2 < 3; ++k2) {
        int c = tid + k2*512;
        int f = (c >= EMBD) ? c - EMBD : c;
        float v = sPool[c];
        p0 += v * Wc[f*2 + 0];
        p1 += v * Wc[f*2 + 1];
    }
    #pragma unroll
    for (int m = 1; m < 64; m <<= 1) { p0 += __shfl_xor(p0, m); p1 += __shfl_xor(p1, m); }
    if (lane == 0) { fbuf[8064 + wave*2] = p0; fbuf[8064 + wave*2 + 1] = p1; }
    __syncthreads();

    // coalesced adj copy-out (30.3 KB contiguous per graph)
    float* og = outp + (size_t)g*NPG*NPG;
    for (int idx = tid; idx < NPG*NPG; idx += 512) {
        int r = idx / NPG, cc = idx - r*NPG;
        og[idx] = fbuf[r*ASTRF + cc];
    }
    if (tid == 0) {
        float q0 = 0.f, q1 = 0.f;
        #pragma unroll
        for (int w = 0; w < 8; ++w) { q0 += fbuf[8064 + w*2]; q1 += fbuf[8064 + w*2 + 1]; }
        outp[ADJSZ + (size_t)g*2 + 0] = q0*(1.0f/87.0f) + bc[0];
        outp[ADJSZ + (size_t)g*2 + 1] = q1*(1.0f/87.0f) + bc[1];
    }
}

extern "C" void kernel_launch(void* const* d_in, const int* in_sizes, int n_in,
                              void* d_out, int out_size, void* d_ws, size_t ws_size,
                              hipStream_t stream) {
    const float* x   = (const float*)d_in[0];
    const int*   ei  = (const int*)d_in[1];
    const float* ew  = (const float*)d_in[2];
    const float* W1  = (const float*)d_in[4];
    const float* b1  = (const float*)d_in[5];
    const float* W2  = (const float*)d_in[6];
    const float* b2  = (const float*)d_in[7];
    const float* W3  = (const float*)d_in[8];
    const float* b3  = (const float*)d_in[9];
    const float* Wc  = (const float*)d_in[10];
    const float* bc  = (const float*)d_in[11];
    float* outp = (float*)d_out;

    char* ws = (char*)d_ws;
    ushort* AbS  = (ushort*)ws;  ws += (size_t)B_GRAPHS*NPGP*NPGP*2;
    ushort* WTs1 = (ushort*)ws;  ws += (size_t)HID*NPGP*2;
    ushort* WTs2 = (ushort*)ws;  ws += (size_t)HID*HID*2;
    ushort* WTs3 = (ushort*)ws;  ws += (size_t)HID*HID*2;

    const int* srcp = ei;
    const int* dstp = ei + NE;

    k_cast_wt<<<dim3(256,3), 256, 0, stream>>>(W1, W2, W3, WTs1, WTs2, WTs3);
    k_buildA <<<B_GRAPHS, 256, 0, stream>>>(srcp, dstp, ew, AbS);
    k_mega   <<<B_GRAPHS, 512, 0, stream>>>(x, AbS, WTs1, WTs2, WTs3,
                                            b1, b2, b3, Wc, bc, outp);
}